// Round 10
// baseline (406.803 us; speedup 1.0000x reference)
//
#include <hip/hip_runtime.h>
#include <hip/hip_bf16.h>
#include <math.h>

#define T_LEN 4096
#define BATCH 16

// ---------------------------------------------------------------------------
// k_gcn: adapter + node projections + A_HAT propagation + relu + node-mean.
// (unchanged from R9 — one-variable discipline; target next round)
// ---------------------------------------------------------------------------
__global__ __launch_bounds__(256) void k_gcn(
    const float* __restrict__ x,      // [B][T][218]
    const float* __restrict__ gcn_w,  // [18][64]
    float* __restrict__ hp)           // [B][64][T]
{
    __shared__ float xt[218 * 36];
    __shared__ float wg[18 * 64];

    const int b   = blockIdx.y;
    const int t0  = blockIdx.x * 32;
    const int tid = threadIdx.x;

    const float* xb = x + ((long)b * T_LEN + t0) * 218;
    #pragma unroll 1
    for (int i = tid; i < 32 * 218; i += 256) {
        const int t = i / 218;
        const int c = i - 218 * t;
        xt[c * 36 + t] = xb[i];
    }
    for (int i = tid; i < 18 * 64; i += 256) wg[i] = gcn_w[i];
    __syncthreads();

    const int dg = tid >> 4;
    const int tt = tid & 15;
    const int d0 = dg * 4;
    const int tb = tt * 2;

    float wr[10][4];
    #pragma unroll
    for (int c = 0; c < 10; ++c)
        *(float4*)wr[c] = *(const float4*)(gcn_w + c * 64 + d0);

    const float cP = 1.0f / 6.0f;
    const float cS = 0.23570226039551584f;   // 1/sqrt(18)
    const float c3 = 1.0f / 3.0f;
    const float cT = 0.4082482904638631f;    // 1/sqrt(6)
    const float cH = 0.5f;

    float h0[4][2];
    #pragma unroll
    for (int di = 0; di < 4; ++di) h0[di][0] = h0[di][1] = 0.f;
    #pragma unroll 1
    for (int c = 0; c < 18; ++c) {
        float wv[4];
        *(float4*)wv = *(const float4*)(&wg[c * 64 + d0]);
        const float2 xv = *(const float2*)(&xt[c * 36 + tb]);
        #pragma unroll
        for (int di = 0; di < 4; ++di) {
            h0[di][0] = fmaf(wv[di], xv.x, h0[di][0]);
            h0[di][1] = fmaf(wv[di], xv.y, h0[di][1]);
        }
    }

    float pool[4][2], star[4][2];
    #pragma unroll
    for (int di = 0; di < 4; ++di) {
        pool[di][0] = pool[di][1] = 0.f;
        star[di][0] = star[di][1] = 0.f;
    }

    #pragma unroll 1
    for (int f = 0; f < 5; ++f) {
        float hn[4][2], hprev[4][2], s12[4][2];
        #pragma unroll
        for (int n = 0; n < 4; ++n) {
            #pragma unroll
            for (int di = 0; di < 4; ++di) hn[di][0] = hn[di][1] = 0.f;
            const int cb = 18 + 10 * (4 * f + n);
            #pragma unroll
            for (int c = 0; c < 10; ++c) {
                const float2 xv = *(const float2*)(&xt[(cb + c) * 36 + tb]);
                #pragma unroll
                for (int di = 0; di < 4; ++di) {
                    hn[di][0] = fmaf(wr[c][di], xv.x, hn[di][0]);
                    hn[di][1] = fmaf(wr[c][di], xv.y, hn[di][1]);
                }
            }
            #pragma unroll
            for (int di = 0; di < 4; ++di)
                #pragma unroll
                for (int ti = 0; ti < 2; ++ti) {
                    const float h = hn[di][ti];
                    if (n == 0) {
                        star[di][ti] += h;
                        s12[di][ti] = h;
                        hprev[di][ti] = h;
                    } else if (n == 1) {
                        const float pa = fmaf(cS, h0[di][ti], c3 * (s12[di][ti] + h));
                        pool[di][ti] += fmaxf(pa, 0.f);
                        s12[di][ti] += h;
                        hprev[di][ti] = h;
                    } else if (n == 2) {
                        const float pb = c3 * (s12[di][ti] + h);
                        pool[di][ti] += fmaxf(pb, 0.f);
                        s12[di][ti] = hprev[di][ti] + h;
                        hprev[di][ti] = h;
                    } else {
                        const float pc = fmaf(cT, h, c3 * s12[di][ti]);
                        const float pe = fmaf(cT, hprev[di][ti], cH * h);
                        pool[di][ti] += fmaxf(pc, 0.f) + fmaxf(pe, 0.f);
                    }
                }
        }
    }

    float* hpb = hp + (long)b * 64 * T_LEN + t0 + tb;
    #pragma unroll
    for (int di = 0; di < 4; ++di) {
        float2 r;
        const float p0a = fmaf(cP, h0[di][0], cS * star[di][0]);
        const float p0b = fmaf(cP, h0[di][1], cS * star[di][1]);
        r.x = (pool[di][0] + fmaxf(p0a, 0.f)) * (1.0f / 21.0f);
        r.y = (pool[di][1] + fmaxf(p0b, 0.f)) * (1.0f / 21.0f);
        *(float2*)(hpb + (long)(d0 + di) * T_LEN) = r;
    }
}

// ---------------------------------------------------------------------------
// k_mstcn: full MSTCN fused, composite-uniform threads, DEEP register tile.
// block 128 = 8 cjg x 16 tt; t-tile 128 (halo 32); thread owns
//   conv:    2 s + 2 m + 4 l channels x 8 t   (832 FMA-cyc per c-iter vs
//            10 ds_read_b128 = 14% LDS duty; 17 weight loads covered 4x)
//   convout: 8 d x 8 t
// grid 512 -> 1 wave/SIMD: per-wave self-sufficiency instead of TLP.
// FINAL adds dense 64->32 + tanh + mean over T.
// ---------------------------------------------------------------------------
template <bool FINAL>
__global__ __launch_bounds__(128) void k_mstcn(
    const float* __restrict__ in,   // [B][64][T]
    const float* __restrict__ ws, const float* __restrict__ bs,
    const float* __restrict__ wm, const float* __restrict__ bm,
    const float* __restrict__ wl, const float* __restrict__ bl,
    const float* __restrict__ wo, const float* __restrict__ bo,
    float* __restrict__ out,        // [B][64][T]  (FINAL=false)
    const float* __restrict__ wd,   // [64][32]    (FINAL=true)
    const float* __restrict__ bd,   // [32]
    float* __restrict__ outp)       // [B][32]     (FINAL=true)
{
    __shared__ float smem[64 * 164]; // x-tile [c][160] stride 164; h aliased

    const int b   = blockIdx.y;
    const int t0  = blockIdx.x * 128;
    const int tid = threadIdx.x;
    const int cjg = tid >> 4;        // 0..7
    const int tt  = tid & 15;        // 8 t at tt*8

    // ---- stage x window [t0-32, t0+128) as [c][160], stride 164 ----
    const float* inb = in + (long)b * 64 * T_LEN;
    #pragma unroll 1
    for (int i = tid; i < 64 * 40; i += 128) {
        const int c = i / 40;
        const int q = i - c * 40;
        const int t = t0 - 32 + q * 4;
        float4 v = make_float4(0.f, 0.f, 0.f, 0.f);
        if (t >= 0) v = *(const float4*)(inb + (long)c * T_LEN + t);
        *(float4*)(&smem[c * 164 + q * 4]) = v;
    }
    __syncthreads();

    // ---- conv phase ----
    const int js = 2 * cjg;
    const int jm = 2 * cjg;
    const int jl = 4 * cjg;

    float as[2][8], am[2][8], al[4][8];
    {
        const float2 b2s = *(const float2*)(bs + js);
        const float2 b2m = *(const float2*)(bm + jm);
        float b4l[4];
        *(float4*)b4l = *(const float4*)(bl + jl);
        #pragma unroll
        for (int i = 0; i < 8; ++i) {
            as[0][i] = b2s.x; as[1][i] = b2s.y;
            am[0][i] = b2m.x; am[1][i] = b2m.y;
            #pragma unroll
            for (int j = 0; j < 4; ++j) al[j][i] = b4l[j];
        }
    }

    float2 wsr[3], wmr[5];
    float  wlr[9][4];
    #pragma unroll
    for (int k = 0; k < 3; ++k) wsr[k] = *(const float2*)(ws + (k * 64) * 16 + js);
    #pragma unroll
    for (int k = 0; k < 5; ++k) wmr[k] = *(const float2*)(wm + (k * 64) * 16 + jm);
    #pragma unroll
    for (int k = 0; k < 9; ++k) *(float4*)wlr[k] = *(const float4*)(wl + (k * 64) * 32 + jl);

    #pragma unroll 1
    for (int c = 0; c < 64; ++c) {
        // window tile cols tt*8 .. tt*8+39  (covers t-32 .. t+7)
        float win[40];
        {
            const float* rb = &smem[c * 164 + tt * 8];
            #pragma unroll
            for (int m = 0; m < 10; ++m)
                *(float4*)(&win[4 * m]) = *(const float4*)(rb + 4 * m);
        }
        const int cn = (c < 63) ? c + 1 : 63;

        // conv_s: x[t-2+k] -> win[30+i+k]
        #pragma unroll
        for (int k = 0; k < 3; ++k) {
            #pragma unroll
            for (int i = 0; i < 8; ++i) {
                const float v = win[30 + i + k];
                as[0][i] = fmaf(wsr[k].x, v, as[0][i]);
                as[1][i] = fmaf(wsr[k].y, v, as[1][i]);
            }
            wsr[k] = *(const float2*)(ws + (k * 64 + cn) * 16 + js);
        }
        // conv_m: x[t-8+2k] -> win[24+i+2k]
        #pragma unroll
        for (int k = 0; k < 5; ++k) {
            #pragma unroll
            for (int i = 0; i < 8; ++i) {
                const float v = win[24 + i + 2 * k];
                am[0][i] = fmaf(wmr[k].x, v, am[0][i]);
                am[1][i] = fmaf(wmr[k].y, v, am[1][i]);
            }
            wmr[k] = *(const float2*)(wm + (k * 64 + cn) * 16 + jm);
        }
        // conv_l: x[t-32+4k] -> win[i+4k]
        #pragma unroll
        for (int k = 0; k < 9; ++k) {
            #pragma unroll
            for (int i = 0; i < 8; ++i) {
                const float v = win[i + 4 * k];
                #pragma unroll
                for (int j = 0; j < 4; ++j)
                    al[j][i] = fmaf(wlr[k][j], v, al[j][i]);
            }
            *(float4*)wlr[k] = *(const float4*)(wl + (k * 64 + cn) * 32 + jl);
        }
    }

    // ---- relu + stage h [64 j][128 t] stride 132 (aliased after barrier) ----
    __syncthreads();
    #pragma unroll
    for (int j = 0; j < 2; ++j) {
        float* p = &smem[(js + j) * 132 + tt * 8];
        *(float4*)(p)     = make_float4(fmaxf(as[j][0], 0.f), fmaxf(as[j][1], 0.f),
                                        fmaxf(as[j][2], 0.f), fmaxf(as[j][3], 0.f));
        *(float4*)(p + 4) = make_float4(fmaxf(as[j][4], 0.f), fmaxf(as[j][5], 0.f),
                                        fmaxf(as[j][6], 0.f), fmaxf(as[j][7], 0.f));
    }
    #pragma unroll
    for (int j = 0; j < 2; ++j) {
        float* p = &smem[(16 + jm + j) * 132 + tt * 8];
        *(float4*)(p)     = make_float4(fmaxf(am[j][0], 0.f), fmaxf(am[j][1], 0.f),
                                        fmaxf(am[j][2], 0.f), fmaxf(am[j][3], 0.f));
        *(float4*)(p + 4) = make_float4(fmaxf(am[j][4], 0.f), fmaxf(am[j][5], 0.f),
                                        fmaxf(am[j][6], 0.f), fmaxf(am[j][7], 0.f));
    }
    #pragma unroll
    for (int j = 0; j < 4; ++j) {
        float* p = &smem[(32 + jl + j) * 132 + tt * 8];
        *(float4*)(p)     = make_float4(fmaxf(al[j][0], 0.f), fmaxf(al[j][1], 0.f),
                                        fmaxf(al[j][2], 0.f), fmaxf(al[j][3], 0.f));
        *(float4*)(p + 4) = make_float4(fmaxf(al[j][4], 0.f), fmaxf(al[j][5], 0.f),
                                        fmaxf(al[j][6], 0.f), fmaxf(al[j][7], 0.f));
    }
    __syncthreads();

    // ---- conv_out 64->64 (no relu): thread = 8 d x 8 t ----
    const int d0 = cjg * 8;
    float o[8][8];
    {
        float bv[8];
        *(float4*)(&bv[0]) = *(const float4*)(bo + d0);
        *(float4*)(&bv[4]) = *(const float4*)(bo + d0 + 4);
        #pragma unroll
        for (int di = 0; di < 8; ++di)
            #pragma unroll
            for (int i = 0; i < 8; ++i) o[di][i] = bv[di];
    }
    #pragma unroll 2
    for (int j = 0; j < 64; ++j) {
        float wv[8], hv[8];
        *(float4*)(&wv[0]) = *(const float4*)(wo + j * 64 + d0);
        *(float4*)(&wv[4]) = *(const float4*)(wo + j * 64 + d0 + 4);
        *(float4*)(&hv[0]) = *(const float4*)(&smem[j * 132 + tt * 8]);
        *(float4*)(&hv[4]) = *(const float4*)(&smem[j * 132 + tt * 8 + 4]);
        #pragma unroll
        for (int di = 0; di < 8; ++di)
            #pragma unroll
            for (int i = 0; i < 8; ++i)
                o[di][i] = fmaf(wv[di], hv[i], o[di][i]);
    }

    if (!FINAL) {
        float* ob = out + (long)b * 64 * T_LEN + t0 + tt * 8;
        #pragma unroll
        for (int di = 0; di < 8; ++di) {
            float* p = ob + (long)(d0 + di) * T_LEN;
            *(float4*)(p)     = make_float4(o[di][0], o[di][1], o[di][2], o[di][3]);
            *(float4*)(p + 4) = make_float4(o[di][4], o[di][5], o[di][6], o[di][7]);
        }
    } else {
        // ---- stage t2 [64 d][128 t], then dense 64->32 + tanh + mean ----
        __syncthreads();
        #pragma unroll
        for (int di = 0; di < 8; ++di) {
            float* p = &smem[(d0 + di) * 132 + tt * 8];
            *(float4*)(p)     = make_float4(o[di][0], o[di][1], o[di][2], o[di][3]);
            *(float4*)(p + 4) = make_float4(o[di][4], o[di][5], o[di][6], o[di][7]);
        }
        __syncthreads();

        // thread = one t-column (128 threads), all 32 e in registers
        float f[32];
        #pragma unroll
        for (int e = 0; e < 8; ++e) {
            *(float4*)(&f[4 * e]) = make_float4(0.f, 0.f, 0.f, 0.f);
        }
        *(float4*)(&f[0])  = *(const float4*)(bd + 0);
        *(float4*)(&f[4])  = *(const float4*)(bd + 4);
        *(float4*)(&f[8])  = *(const float4*)(bd + 8);
        *(float4*)(&f[12]) = *(const float4*)(bd + 12);
        *(float4*)(&f[16]) = *(const float4*)(bd + 16);
        *(float4*)(&f[20]) = *(const float4*)(bd + 20);
        *(float4*)(&f[24]) = *(const float4*)(bd + 24);
        *(float4*)(&f[28]) = *(const float4*)(bd + 28);

        #pragma unroll 2
        for (int d = 0; d < 64; ++d) {
            const float hv = smem[d * 132 + tid];     // lane-varying, stride-1
            const float* wrow = wd + d * 32;          // wave-uniform
            #pragma unroll
            for (int e = 0; e < 32; ++e) f[e] = fmaf(wrow[e], hv, f[e]);
        }

        const int lane = tid & 63;
        #pragma unroll 1
        for (int e = 0; e < 32; ++e) {
            float v = tanhf(f[e]) * (1.0f / (float)T_LEN);
            v += __shfl_down(v, 32);
            v += __shfl_down(v, 16);
            v += __shfl_down(v, 8);
            v += __shfl_down(v, 4);
            v += __shfl_down(v, 2);
            v += __shfl_down(v, 1);
            if (lane == 0) atomicAdd(&outp[b * 32 + e], v);
        }
    }
}

extern "C" void kernel_launch(void* const* d_in, const int* in_sizes, int n_in,
                              void* d_out, int out_size, void* d_ws, size_t ws_size,
                              hipStream_t stream) {
    const float* x     = (const float*)d_in[0];
    const float* gcn_w = (const float*)d_in[1];
    const float* wd    = (const float*)d_in[2];
    const float* bd    = (const float*)d_in[3];
    const float* t1_ws = (const float*)d_in[4];
    const float* t1_bs = (const float*)d_in[5];
    const float* t1_wm = (const float*)d_in[6];
    const float* t1_bm = (const float*)d_in[7];
    const float* t1_wl = (const float*)d_in[8];
    const float* t1_bl = (const float*)d_in[9];
    const float* t1_wo = (const float*)d_in[10];
    const float* t1_bo = (const float*)d_in[11];
    const float* t2_ws = (const float*)d_in[12];
    const float* t2_bs = (const float*)d_in[13];
    const float* t2_wm = (const float*)d_in[14];
    const float* t2_bm = (const float*)d_in[15];
    const float* t2_wl = (const float*)d_in[16];
    const float* t2_bl = (const float*)d_in[17];
    const float* t2_wo = (const float*)d_in[18];
    const float* t2_bo = (const float*)d_in[19];

    float* b0 = (float*)d_ws;                          // [16][64][4096]
    float* b1 = b0 + (size_t)BATCH * 64 * T_LEN;       // [16][64][4096]

    hipMemsetAsync(d_out, 0, (size_t)out_size * sizeof(float), stream);

    k_gcn<<<dim3(T_LEN / 32, BATCH), 256, 0, stream>>>(x, gcn_w, b0);

    k_mstcn<false><<<dim3(T_LEN / 128, BATCH), 128, 0, stream>>>(
        b0, t1_ws, t1_bs, t1_wm, t1_bm, t1_wl, t1_bl, t1_wo, t1_bo,
        b1, nullptr, nullptr, nullptr);

    k_mstcn<true><<<dim3(T_LEN / 128, BATCH), 128, 0, stream>>>(
        b1, t2_ws, t2_bs, t2_wm, t2_bm, t2_wl, t2_bl, t2_wo, t2_bo,
        nullptr, wd, bd, (float*)d_out);
}